// Round 10
// baseline (213.588 us; speedup 1.0000x reference)
//
#include <hip/hip_runtime.h>

#define N_NODES 100000
#define N_EDGES 1600000
#define D 128           // D_IN == D_OUT == 128
#define D4 32           // D in float4 units

#define BM 128                                   // gemm rows per block
#define GEMM_BLOCKS ((N_NODES + BM - 1) / BM)    // 782 (tail block: 32 rows)
#define LDK 136                                  // padded LDS row (bf16 elems)

typedef __attribute__((ext_vector_type(8))) short short8;   // 8 bf16 = 4 VGPRs (MFMA A/B frag)
typedef __attribute__((ext_vector_type(4))) float floatx4;  // MFMA C/D frag

// ---- bf16 helpers (bit-level, RNE pack / cheap unpack) ---------------------
__device__ __forceinline__ unsigned short f2bf(float f) {
    unsigned int b = __float_as_uint(f);
    b += 0x7FFFu + ((b >> 16) & 1u);           // round to nearest even
    return (unsigned short)(b >> 16);
}
__device__ __forceinline__ float bf2f(unsigned short u) {
    return __uint_as_float((unsigned int)u << 16);
}

// ---------------------------------------------------------------------------
// W^T prep (once): wt[n*128+k] = bf16(W[k*128+n]). 32 KB output, trivial.
// ---------------------------------------------------------------------------
__global__ __launch_bounds__(256) void w_prep(
    const float* __restrict__ W, unsigned short* __restrict__ wt)
{
    int idx = blockIdx.x * 256 + threadIdx.x;   // 0..16383
    int k = idx >> 7, n = idx & 127;
    wt[(size_t)n * D + k] = f2bf(W[idx]);
}

// ---------------------------------------------------------------------------
// Fused: support = bf16(x) @ bf16(W) via MFMA  +  edge linked-list build.
// W^T read DIRECT from global (32 KB, L1-resident, shared by all blocks) —
// LDS holds only the x tile (34 KB) -> 4 blocks/CU, 16 waves/CU.
// ---------------------------------------------------------------------------
__global__ __launch_bounds__(256, 4) void gemm_build(
    const float* __restrict__ x, const unsigned short* __restrict__ wt,
    unsigned short* __restrict__ sup,
    const int* __restrict__ row, const int* __restrict__ col,
    const float* __restrict__ ew,
    int* __restrict__ head, int4* __restrict__ entries)
{
    __shared__ unsigned short xs[BM * LDK];      // 34.0 KB

    const int tid = threadIdx.x;
    const int brow = blockIdx.x * BM;

    // stage x tile (fp32 -> bf16), 128 rows x 32 float4, zero-pad tail rows
    {
        const float4* xv = reinterpret_cast<const float4*>(x);
        #pragma unroll
        for (int i = 0; i < 16; ++i) {
            int idx = tid + i * 256;             // 0..4095
            int r = idx >> 5, k4 = idx & 31;
            int gr = brow + r;
            float4 v = (gr < N_NODES) ? xv[(size_t)gr * D4 + k4]
                                      : make_float4(0.f, 0.f, 0.f, 0.f);
            ushort4 p;
            p.x = f2bf(v.x); p.y = f2bf(v.y); p.z = f2bf(v.z); p.w = f2bf(v.w);
            *reinterpret_cast<ushort4*>(&xs[r * LDK + k4 * 4]) = p;
        }
    }
    __syncthreads();

    const int wave = tid >> 6;
    const int lane = tid & 63;
    const int l15  = lane & 15;
    const int lkg  = lane >> 4;                  // K sub-group 0..3
    const int lk8  = lkg * 8;

    floatx4 acc[2][8];
    #pragma unroll
    for (int m = 0; m < 2; ++m)
        #pragma unroll
        for (int n = 0; n < 8; ++n) acc[m][n] = (floatx4){0.f, 0.f, 0.f, 0.f};

    const short8* bv = reinterpret_cast<const short8*>(wt);
    const int wrow = wave * 32;
    #pragma unroll
    for (int kk = 0; kk < 4; ++kk) {
        int kb = kk * 32 + lk8;
        // A frags from LDS: row = lane&15 (+16 for m=1), k = kb..kb+7
        short8 a0 = *reinterpret_cast<const short8*>(&xs[(wrow + l15) * LDK + kb]);
        short8 a1 = *reinterpret_cast<const short8*>(&xs[(wrow + 16 + l15) * LDK + kb]);
        #pragma unroll
        for (int n = 0; n < 8; ++n) {
            // B frag direct from global W^T: col = n*16+(lane&15), same k range
            short8 b = bv[(n * 16 + l15) * 16 + kk * 4 + lkg];
            acc[0][n] = __builtin_amdgcn_mfma_f32_16x16x32_bf16(a0, b, acc[0][n], 0, 0, 0);
            acc[1][n] = __builtin_amdgcn_mfma_f32_16x16x32_bf16(a1, b, acc[1][n], 0, 0, 0);
        }
    }

    // epilogue: D col = lane&15, row = (lane>>4)*4 + r  (m89-verified)
    const int rbase = brow + wrow + lkg * 4;
    #pragma unroll
    for (int m = 0; m < 2; ++m) {
        #pragma unroll
        for (int r = 0; r < 4; ++r) {
            int grow = rbase + m * 16 + r;
            if (grow < N_NODES) {
                #pragma unroll
                for (int n = 0; n < 8; ++n)
                    sup[(size_t)grow * D + n * 16 + l15] = f2bf(acc[m][n][r]);
            }
        }
    }

    // fused edge-list build (grid-stride; kernel boundary orders it vs gather)
    for (int e = blockIdx.x * 256 + tid; e < N_EDGES; e += GEMM_BLOCKS * 256) {
        int nx = atomicExch(&head[row[e]], e);
        entries[e] = make_int4(nx, col[e], __float_as_int(ew[e]), 0);
    }
}

// ---------------------------------------------------------------------------
// Gather: half-wave (32 lanes) per node chases the list. Per edge: one int4
// entry fetch (broadcast) + bf16 support row (32 x ushort4 = 256 B coalesced).
// ---------------------------------------------------------------------------
__global__ __launch_bounds__(256) void gather_list(
    const int* __restrict__ head, const int4* __restrict__ entries,
    const unsigned short* __restrict__ sup, float* __restrict__ out)
{
    const int half = threadIdx.x >> 5;          // 0..7
    const int lane = threadIdx.x & 31;
    const int node = blockIdx.x * 8 + half;     // grid exact: 12500*8 = N_NODES

    float4 acc = {0.f, 0.f, 0.f, 0.f};

    int e = head[node];
    while (e >= 0) {
        int4 en = entries[e];                   // next, col, w_bits (one line)
        float w = __int_as_float(en.z);
        ushort4 s = reinterpret_cast<const ushort4*>(sup + (size_t)en.y * D)[lane];
        acc.x = fmaf(w, bf2f(s.x), acc.x);
        acc.y = fmaf(w, bf2f(s.y), acc.y);
        acc.z = fmaf(w, bf2f(s.z), acc.z);
        acc.w = fmaf(w, bf2f(s.w), acc.w);
        e = en.x;
    }
    reinterpret_cast<float4*>(out)[(size_t)node * D4 + lane] = acc;
}

// ---------------------------------------------------------------------------
// Fallback path (ws too small): VALU gemm + atomic scatter (proven R3/R8).
// ---------------------------------------------------------------------------
__device__ __forceinline__ void fma4(float4& a, float s, const float4& b) {
    a.x = fmaf(s, b.x, a.x);
    a.y = fmaf(s, b.y, a.y);
    a.z = fmaf(s, b.z, a.z);
    a.w = fmaf(s, b.w, a.w);
}

__global__ __launch_bounds__(256) void gemm_xw(
    const float* __restrict__ x, const float* __restrict__ W,
    unsigned short* __restrict__ sup)
{
    __shared__ float4 xs[32 * D4];
    const int tid = threadIdx.x;
    const int block_row = blockIdx.x * 32;

    const float4* xv = reinterpret_cast<const float4*>(x) + (size_t)block_row * D4;
    #pragma unroll
    for (int i = 0; i < 4; ++i) xs[tid + i * 256] = xv[tid + i * 256];
    __syncthreads();

    const int cg = tid & 31;
    const int rg = tid >> 5;
    const float4* Wv = reinterpret_cast<const float4*>(W);

    float4 acc0 = {0.f, 0.f, 0.f, 0.f};
    float4 acc1 = acc0, acc2 = acc0, acc3 = acc0;

    const int r0 = rg * 4;
    #pragma unroll 8
    for (int k4 = 0; k4 < D4; ++k4) {
        float4 xa = xs[(r0 + 0) * D4 + k4];
        float4 xb = xs[(r0 + 1) * D4 + k4];
        float4 xc = xs[(r0 + 2) * D4 + k4];
        float4 xd = xs[(r0 + 3) * D4 + k4];
        float4 w0 = Wv[(k4 * 4 + 0) * D4 + cg];
        fma4(acc0, xa.x, w0); fma4(acc1, xb.x, w0);
        fma4(acc2, xc.x, w0); fma4(acc3, xd.x, w0);
        float4 w1 = Wv[(k4 * 4 + 1) * D4 + cg];
        fma4(acc0, xa.y, w1); fma4(acc1, xb.y, w1);
        fma4(acc2, xc.y, w1); fma4(acc3, xd.y, w1);
        float4 w2 = Wv[(k4 * 4 + 2) * D4 + cg];
        fma4(acc0, xa.z, w2); fma4(acc1, xb.z, w2);
        fma4(acc2, xc.z, w2); fma4(acc3, xd.z, w2);
        float4 w3 = Wv[(k4 * 4 + 3) * D4 + cg];
        fma4(acc0, xa.w, w3); fma4(acc1, xb.w, w3);
        fma4(acc2, xc.w, w3); fma4(acc3, xd.w, w3);
    }

    ushort4 p;
    #define STORE_BF16(ACC, R)                                            \
        p.x = f2bf(ACC.x); p.y = f2bf(ACC.y);                             \
        p.z = f2bf(ACC.z); p.w = f2bf(ACC.w);                             \
        *reinterpret_cast<ushort4*>(sup + (size_t)(block_row + r0 + R) * D + cg * 4) = p;
    STORE_BF16(acc0, 0)
    STORE_BF16(acc1, 1)
    STORE_BF16(acc2, 2)
    STORE_BF16(acc3, 3)
    #undef STORE_BF16
}

__global__ __launch_bounds__(256) void scatter_edges(
    const int* __restrict__ row, const int* __restrict__ col,
    const float* __restrict__ ew, const unsigned short* __restrict__ sup,
    float* __restrict__ out)
{
    const int e = blockIdx.x * 8 + (threadIdx.x >> 5);
    if (e >= N_EDGES) return;
    const int lane = threadIdx.x & 31;

    const int r = row[e];
    const int c = col[e];
    const float w = ew[e];
    ushort4 s = reinterpret_cast<const ushort4*>(sup + (size_t)c * D)[lane];
    float* o = out + (size_t)r * D + lane * 4;
    atomicAdd(o + 0, w * bf2f(s.x));
    atomicAdd(o + 1, w * bf2f(s.y));
    atomicAdd(o + 2, w * bf2f(s.z));
    atomicAdd(o + 3, w * bf2f(s.w));
}

extern "C" void kernel_launch(void* const* d_in, const int* in_sizes, int n_in,
                              void* d_out, int out_size, void* d_ws, size_t ws_size,
                              hipStream_t stream)
{
    const float* x      = (const float*)d_in[0];   // [N_NODES, 128]
    const int*   row    = (const int*)d_in[1];     // [N_EDGES]
    const int*   col    = (const int*)d_in[2];     // [N_EDGES]
    const float* ew     = (const float*)d_in[3];   // [N_EDGES]
    const float* weight = (const float*)d_in[4];   // [128, 128]
    float* out = (float*)d_out;                    // [N_NODES, 128]

    char* ws = (char*)d_ws;
    const size_t off_sup     = 0;                                      // 25.6 MB
    const size_t off_head    = off_sup + (size_t)N_NODES * D * 2;      // 400 KB
    const size_t off_entries = off_head + (((size_t)N_NODES * 4 + 15) & ~(size_t)15);
    const size_t off_wt      = off_entries + (size_t)N_EDGES * 16;     // 32 KB
    const size_t required    = off_wt + (size_t)D * D * 2;

    unsigned short* sup = (unsigned short*)(ws + off_sup);

    if (ws_size >= required) {
        int*  head    = (int*)(ws + off_head);
        int4* entries = (int4*)(ws + off_entries);
        unsigned short* wt = (unsigned short*)(ws + off_wt);

        hipMemsetAsync(head, 0xFF, (size_t)N_NODES * 4, stream);       // head = -1
        w_prep<<<D * D / 256, 256, 0, stream>>>(weight, wt);

        // fused MFMA gemm + edge-list build
        gemm_build<<<GEMM_BLOCKS, 256, 0, stream>>>(
            x, wt, sup, row, col, ew, head, entries);

        // gather: writes every output row (no out memset needed)
        gather_list<<<N_NODES / 8, 256, 0, stream>>>(head, entries, sup, out);
    } else {
        gemm_xw<<<N_NODES / 32, 256, 0, stream>>>(x, weight, sup);
        hipMemsetAsync(d_out, 0, (size_t)N_NODES * D * sizeof(float), stream);
        scatter_edges<<<N_EDGES / 8, 256, 0, stream>>>(row, col, ew, sup, out);
    }
}

// Round 11
// 184.151 us; speedup vs baseline: 1.1599x; 1.1599x over previous
//
#include <hip/hip_runtime.h>

#define N_NODES 100000
#define N_EDGES 1600000
#define D 128           // D_IN == D_OUT == 128
#define D4 32           // D in float4 units

#define BM 128                                   // gemm rows per block
#define GEMM_BLOCKS ((N_NODES + BM - 1) / BM)    // 782 (tail block: 32 rows)
#define BUILD_BLOCKS 256                         // edge-list builder blocks
#define TOTAL_BLOCKS (BUILD_BLOCKS + GEMM_BLOCKS)
#define LDK 136                                  // padded LDS row (bf16 elems)

typedef __attribute__((ext_vector_type(8))) short short8;   // 8 bf16 = 4 VGPRs (MFMA A/B frag)
typedef __attribute__((ext_vector_type(4))) float floatx4;  // MFMA C/D frag

// ---- bf16 helpers (bit-level, RNE pack / cheap unpack) ---------------------
__device__ __forceinline__ unsigned short f2bf(float f) {
    unsigned int b = __float_as_uint(f);
    b += 0x7FFFu + ((b >> 16) & 1u);           // round to nearest even
    return (unsigned short)(b >> 16);
}
__device__ __forceinline__ float bf2f(unsigned short u) {
    return __uint_as_float((unsigned int)u << 16);
}

// ---------------------------------------------------------------------------
// W^T prep (once): wt[n*128+k] = bf16(W[k*128+n]). 32 KB output, trivial.
// ---------------------------------------------------------------------------
__global__ __launch_bounds__(256) void w_prep(
    const float* __restrict__ W, unsigned short* __restrict__ wt)
{
    int idx = blockIdx.x * 256 + threadIdx.x;   // 0..16383
    int k = idx >> 7, n = idx & 127;
    wt[(size_t)n * D + k] = f2bf(W[idx]);
}

// ---------------------------------------------------------------------------
// Mega kernel, block-specialized:
//   blocks [0, BUILD_BLOCKS): edge linked-list build (grid-stride)
//   blocks [BUILD_BLOCKS, TOTAL_BLOCKS): MFMA GEMM tile (R10 structure)
// Build blocks dispatch FIRST -> resident from t=0, their atomic latency
// overlaps the GEMM blocks' staging/MFMA on the same CUs.
// ---------------------------------------------------------------------------
__global__ __launch_bounds__(256, 4) void mega(
    const float* __restrict__ x, const unsigned short* __restrict__ wt,
    unsigned short* __restrict__ sup,
    const int* __restrict__ row, const int* __restrict__ col,
    const float* __restrict__ ew,
    int* __restrict__ head, int4* __restrict__ entries)
{
    __shared__ unsigned short xs[BM * LDK];      // 34.0 KB

    const int tid = threadIdx.x;

    if (blockIdx.x < BUILD_BLOCKS) {
        // ---- builder path: 65536 threads, ~24 edges each, coalesced reads
        for (int e = blockIdx.x * 256 + tid; e < N_EDGES; e += BUILD_BLOCKS * 256) {
            int nx = atomicExch(&head[row[e]], e);
            entries[e] = make_int4(nx, col[e], __float_as_int(ew[e]), 0);
        }
        return;
    }

    // ---- GEMM path
    const int brow = (blockIdx.x - BUILD_BLOCKS) * BM;

    // stage x tile (fp32 -> bf16), 128 rows x 32 float4, zero-pad tail rows
    {
        const float4* xv = reinterpret_cast<const float4*>(x);
        #pragma unroll
        for (int i = 0; i < 16; ++i) {
            int idx = tid + i * 256;             // 0..4095
            int r = idx >> 5, k4 = idx & 31;
            int gr = brow + r;
            float4 v = (gr < N_NODES) ? xv[(size_t)gr * D4 + k4]
                                      : make_float4(0.f, 0.f, 0.f, 0.f);
            ushort4 p;
            p.x = f2bf(v.x); p.y = f2bf(v.y); p.z = f2bf(v.z); p.w = f2bf(v.w);
            *reinterpret_cast<ushort4*>(&xs[r * LDK + k4 * 4]) = p;
        }
    }
    __syncthreads();

    const int wave = tid >> 6;
    const int lane = tid & 63;
    const int l15  = lane & 15;
    const int lkg  = lane >> 4;                  // K sub-group 0..3

    floatx4 acc[2][8];
    #pragma unroll
    for (int m = 0; m < 2; ++m)
        #pragma unroll
        for (int n = 0; n < 8; ++n) acc[m][n] = (floatx4){0.f, 0.f, 0.f, 0.f};

    const short8* bv = reinterpret_cast<const short8*>(wt);
    const int wrow = wave * 32;
    #pragma unroll
    for (int kk = 0; kk < 4; ++kk) {
        int kb = kk * 32 + lkg * 8;
        short8 a0 = *reinterpret_cast<const short8*>(&xs[(wrow + l15) * LDK + kb]);
        short8 a1 = *reinterpret_cast<const short8*>(&xs[(wrow + 16 + l15) * LDK + kb]);
        #pragma unroll
        for (int n = 0; n < 8; ++n) {
            short8 b = bv[(n * 16 + l15) * 16 + kk * 4 + lkg];
            acc[0][n] = __builtin_amdgcn_mfma_f32_16x16x32_bf16(a0, b, acc[0][n], 0, 0, 0);
            acc[1][n] = __builtin_amdgcn_mfma_f32_16x16x32_bf16(a1, b, acc[1][n], 0, 0, 0);
        }
    }

    // epilogue: D col = lane&15, row = (lane>>4)*4 + r  (m89-verified)
    const int rbase = brow + wrow + lkg * 4;
    #pragma unroll
    for (int m = 0; m < 2; ++m) {
        #pragma unroll
        for (int r = 0; r < 4; ++r) {
            int grow = rbase + m * 16 + r;
            if (grow < N_NODES) {
                #pragma unroll
                for (int n = 0; n < 8; ++n)
                    sup[(size_t)grow * D + n * 16 + l15] = f2bf(acc[m][n][r]);
            }
        }
    }
}

// ---------------------------------------------------------------------------
// Gather: each half-wave owns FOUR nodes' chains, interleaved -> 4 independent
// pointer-chase chains in flight. Chain state is half-wave-uniform; finished
// chains read entries[0] as a cache-hot dummy with weight forced to 0.
// ---------------------------------------------------------------------------
__global__ __launch_bounds__(256) void gather_list(
    const int* __restrict__ head, const int4* __restrict__ entries,
    const unsigned short* __restrict__ sup, float* __restrict__ out)
{
    const int half = threadIdx.x >> 5;          // 0..7
    const int lane = threadIdx.x & 31;
    const int nb = blockIdx.x * 32 + half * 4;  // 3125 blocks * 32 = N_NODES

    float4 a0 = {0.f, 0.f, 0.f, 0.f};
    float4 a1 = a0, a2 = a0, a3 = a0;

    int e0 = head[nb + 0];
    int e1 = head[nb + 1];
    int e2 = head[nb + 2];
    int e3 = head[nb + 3];

    while (e0 >= 0 || e1 >= 0 || e2 >= 0 || e3 >= 0) {
        int4 q0 = entries[e0 >= 0 ? e0 : 0];
        int4 q1 = entries[e1 >= 0 ? e1 : 0];
        int4 q2 = entries[e2 >= 0 ? e2 : 0];
        int4 q3 = entries[e3 >= 0 ? e3 : 0];

        ushort4 s0 = reinterpret_cast<const ushort4*>(sup + (size_t)q0.y * D)[lane];
        ushort4 s1 = reinterpret_cast<const ushort4*>(sup + (size_t)q1.y * D)[lane];
        ushort4 s2 = reinterpret_cast<const ushort4*>(sup + (size_t)q2.y * D)[lane];
        ushort4 s3 = reinterpret_cast<const ushort4*>(sup + (size_t)q3.y * D)[lane];

        float w0 = (e0 >= 0) ? __int_as_float(q0.z) : 0.f;
        float w1 = (e1 >= 0) ? __int_as_float(q1.z) : 0.f;
        float w2 = (e2 >= 0) ? __int_as_float(q2.z) : 0.f;
        float w3 = (e3 >= 0) ? __int_as_float(q3.z) : 0.f;

        a0.x = fmaf(w0, bf2f(s0.x), a0.x); a0.y = fmaf(w0, bf2f(s0.y), a0.y);
        a0.z = fmaf(w0, bf2f(s0.z), a0.z); a0.w = fmaf(w0, bf2f(s0.w), a0.w);
        a1.x = fmaf(w1, bf2f(s1.x), a1.x); a1.y = fmaf(w1, bf2f(s1.y), a1.y);
        a1.z = fmaf(w1, bf2f(s1.z), a1.z); a1.w = fmaf(w1, bf2f(s1.w), a1.w);
        a2.x = fmaf(w2, bf2f(s2.x), a2.x); a2.y = fmaf(w2, bf2f(s2.y), a2.y);
        a2.z = fmaf(w2, bf2f(s2.z), a2.z); a2.w = fmaf(w2, bf2f(s2.w), a2.w);
        a3.x = fmaf(w3, bf2f(s3.x), a3.x); a3.y = fmaf(w3, bf2f(s3.y), a3.y);
        a3.z = fmaf(w3, bf2f(s3.z), a3.z); a3.w = fmaf(w3, bf2f(s3.w), a3.w);

        e0 = (e0 >= 0) ? q0.x : -1;
        e1 = (e1 >= 0) ? q1.x : -1;
        e2 = (e2 >= 0) ? q2.x : -1;
        e3 = (e3 >= 0) ? q3.x : -1;
    }

    float4* ov = reinterpret_cast<float4*>(out);
    ov[(size_t)(nb + 0) * D4 + lane] = a0;
    ov[(size_t)(nb + 1) * D4 + lane] = a1;
    ov[(size_t)(nb + 2) * D4 + lane] = a2;
    ov[(size_t)(nb + 3) * D4 + lane] = a3;
}

// ---------------------------------------------------------------------------
// Fallback path (ws too small): VALU gemm + atomic scatter (proven R3/R8).
// ---------------------------------------------------------------------------
__device__ __forceinline__ void fma4(float4& a, float s, const float4& b) {
    a.x = fmaf(s, b.x, a.x);
    a.y = fmaf(s, b.y, a.y);
    a.z = fmaf(s, b.z, a.z);
    a.w = fmaf(s, b.w, a.w);
}

__global__ __launch_bounds__(256) void gemm_xw(
    const float* __restrict__ x, const float* __restrict__ W,
    unsigned short* __restrict__ sup)
{
    __shared__ float4 xs[32 * D4];
    const int tid = threadIdx.x;
    const int block_row = blockIdx.x * 32;

    const float4* xv = reinterpret_cast<const float4*>(x) + (size_t)block_row * D4;
    #pragma unroll
    for (int i = 0; i < 4; ++i) xs[tid + i * 256] = xv[tid + i * 256];
    __syncthreads();

    const int cg = tid & 31;
    const int rg = tid >> 5;
    const float4* Wv = reinterpret_cast<const float4*>(W);

    float4 acc0 = {0.f, 0.f, 0.f, 0.f};
    float4 acc1 = acc0, acc2 = acc0, acc3 = acc0;

    const int r0 = rg * 4;
    #pragma unroll 8
    for (int k4 = 0; k4 < D4; ++k4) {
        float4 xa = xs[(r0 + 0) * D4 + k4];
        float4 xb = xs[(r0 + 1) * D4 + k4];
        float4 xc = xs[(r0 + 2) * D4 + k4];
        float4 xd = xs[(r0 + 3) * D4 + k4];
        float4 w0 = Wv[(k4 * 4 + 0) * D4 + cg];
        fma4(acc0, xa.x, w0); fma4(acc1, xb.x, w0);
        fma4(acc2, xc.x, w0); fma4(acc3, xd.x, w0);
        float4 w1 = Wv[(k4 * 4 + 1) * D4 + cg];
        fma4(acc0, xa.y, w1); fma4(acc1, xb.y, w1);
        fma4(acc2, xc.y, w1); fma4(acc3, xd.y, w1);
        float4 w2 = Wv[(k4 * 4 + 2) * D4 + cg];
        fma4(acc0, xa.z, w2); fma4(acc1, xb.z, w2);
        fma4(acc2, xc.z, w2); fma4(acc3, xd.z, w2);
        float4 w3 = Wv[(k4 * 4 + 3) * D4 + cg];
        fma4(acc0, xa.w, w3); fma4(acc1, xb.w, w3);
        fma4(acc2, xc.w, w3); fma4(acc3, xd.w, w3);
    }

    ushort4 p;
    #define STORE_BF16(ACC, R)                                            \
        p.x = f2bf(ACC.x); p.y = f2bf(ACC.y);                             \
        p.z = f2bf(ACC.z); p.w = f2bf(ACC.w);                             \
        *reinterpret_cast<ushort4*>(sup + (size_t)(block_row + r0 + R) * D + cg * 4) = p;
    STORE_BF16(acc0, 0)
    STORE_BF16(acc1, 1)
    STORE_BF16(acc2, 2)
    STORE_BF16(acc3, 3)
    #undef STORE_BF16
}

__global__ __launch_bounds__(256) void scatter_edges(
    const int* __restrict__ row, const int* __restrict__ col,
    const float* __restrict__ ew, const unsigned short* __restrict__ sup,
    float* __restrict__ out)
{
    const int e = blockIdx.x * 8 + (threadIdx.x >> 5);
    if (e >= N_EDGES) return;
    const int lane = threadIdx.x & 31;

    const int r = row[e];
    const int c = col[e];
    const float w = ew[e];
    ushort4 s = reinterpret_cast<const ushort4*>(sup + (size_t)c * D)[lane];
    float* o = out + (size_t)r * D + lane * 4;
    atomicAdd(o + 0, w * bf2f(s.x));
    atomicAdd(o + 1, w * bf2f(s.y));
    atomicAdd(o + 2, w * bf2f(s.z));
    atomicAdd(o + 3, w * bf2f(s.w));
}

extern "C" void kernel_launch(void* const* d_in, const int* in_sizes, int n_in,
                              void* d_out, int out_size, void* d_ws, size_t ws_size,
                              hipStream_t stream)
{
    const float* x      = (const float*)d_in[0];   // [N_NODES, 128]
    const int*   row    = (const int*)d_in[1];     // [N_EDGES]
    const int*   col    = (const int*)d_in[2];     // [N_EDGES]
    const float* ew     = (const float*)d_in[3];   // [N_EDGES]
    const float* weight = (const float*)d_in[4];   // [128, 128]
    float* out = (float*)d_out;                    // [N_NODES, 128]

    char* ws = (char*)d_ws;
    const size_t off_sup     = 0;                                      // 25.6 MB
    const size_t off_head    = off_sup + (size_t)N_NODES * D * 2;      // 400 KB
    const size_t off_entries = off_head + (((size_t)N_NODES * 4 + 15) & ~(size_t)15);
    const size_t off_wt      = off_entries + (size_t)N_EDGES * 16;     // 32 KB
    const size_t required    = off_wt + (size_t)D * D * 2;

    unsigned short* sup = (unsigned short*)(ws + off_sup);

    if (ws_size >= required) {
        int*  head    = (int*)(ws + off_head);
        int4* entries = (int4*)(ws + off_entries);
        unsigned short* wt = (unsigned short*)(ws + off_wt);

        hipMemsetAsync(head, 0xFF, (size_t)N_NODES * 4, stream);       // head = -1
        w_prep<<<D * D / 256, 256, 0, stream>>>(weight, wt);

        // block-specialized: builders (first) + MFMA gemm tiles, overlapped
        mega<<<TOTAL_BLOCKS, 256, 0, stream>>>(
            x, wt, sup, row, col, ew, head, entries);

        // gather: writes every output row (no out memset needed)
        gather_list<<<N_NODES / 32, 256, 0, stream>>>(head, entries, sup, out);
    } else {
        gemm_xw<<<N_NODES / 32, 256, 0, stream>>>(x, weight, sup);
        hipMemsetAsync(d_out, 0, (size_t)N_NODES * D * sizeof(float), stream);
        scatter_edges<<<N_EDGES / 8, 256, 0, stream>>>(row, col, ew, sup, out);
    }
}